// Round 4
// baseline (194.766 us; speedup 1.0000x reference)
//
#include <hip/hip_runtime.h>

// Problem constants: h[B,G,D], W[G,D,K], out[B,G,K]
#define Gn   100
#define Bn   256
#define Dn   768
#define Kn   128

typedef __attribute__((ext_vector_type(8))) short short8;
typedef __attribute__((ext_vector_type(4))) float f32x4;

// pack two fp32 -> two bf16 (round-to-nearest, ties away) in 3 VALU
__device__ inline unsigned pack2(float lo, float hi) {
  union { float f; unsigned u; } a, b; a.f = lo; b.f = hi;
  return __builtin_amdgcn_perm(b.u + 0x8000u, a.u + 0x8000u, 0x07060302u);
}

// LDS-free grouped GEMM with fused L2 norms.
// Each wave owns a 32x32 output tile and loads its MFMA fragments DIRECTLY
// from global into registers (no LDS staging, no __syncthreads in the K-loop
// => no vmcnt(0) barrier drain => prefetched loads genuinely stay in flight).
// Intra-block duplication (wn-pair shares A rows, wm-pair shares B cols) is
// served by L1 (8 KB slabs/chunk, same CU). fp32->bf16 conversion in-register.
// Norms: each wave reads its A-rows / B-cols exactly once across the K-loop,
// so per-lane fp32 ssq + quad-reduce (shfl_xor 16,32) gives exact row/col
// norms; designated waves publish to tiny LDS arrays; applied in epilogue.
// grid (4, 2, 100), block 256 (4 waves, 2x2 wave grid).
__global__ __launch_bounds__(256) void groupfc_kernel(
    const float* __restrict__ h, const float* __restrict__ W,
    float* __restrict__ out) {
  const int g    = blockIdx.z;
  const int mt   = blockIdx.x;               // 0..3 (rows of 64)
  const int nt   = blockIdx.y;               // 0..1 (cols of 64)
  const int t    = threadIdx.x;
  const int lane = t & 63;
  const int wave = t >> 6;
  const int wm   = wave >> 1, wn = wave & 1; // 2x2 wave grid, 32x32 per wave
  const int l15  = lane & 15, quad = lane >> 4;

  __shared__ float AssqL[64];                // per-local-row sum(h^2), full D
  __shared__ float BssqL[64];                // per-local-col sum(W^2), full D

  // A fragment source: rows r0, r0+16 at k = c*32 + quad*8 + j  (j=0..7)
  const int r0 = mt * 64 + wm * 32 + l15;    // global b index
  const int n0 = nt * 64 + wn * 32 + l15;    // global k-col index
  const float* ap0 = h + ((size_t)r0 * Gn + g) * Dn + quad * 8;
  const float* ap1 = ap0 + (size_t)16 * Gn * Dn;
  // B fragment source: cols n0, n0+16 at the same k
  const float* bp0 = W + (size_t)g * Dn * Kn + (size_t)(quad * 8) * Kn + n0;
  const float* bp1 = bp0 + 16;

  f32x4 acc00 = {0.f,0.f,0.f,0.f};
  f32x4 acc01 = acc00, acc10 = acc00, acc11 = acc00;
  float as0 = 0.f, as1 = 0.f, bs0 = 0.f, bs1 = 0.f;

  float4 cA0[2], cA1[2]; float cB0[8], cB1[8];   // current chunk regs
  float4 pA0[2], pA1[2]; float pB0[8], pB1[8];   // prefetch chunk regs

  auto load_chunk = [&](int c, float4 (&A0)[2], float4 (&A1)[2],
                        float (&B0)[8], float (&B1)[8]) {
    const float* a0 = ap0 + c * 32;          // A spans only 3 KB: imm offsets
    const float* a1 = ap1 + c * 32;
    A0[0] = *(const float4*)a0; A0[1] = *(const float4*)(a0 + 4);
    A1[0] = *(const float4*)a1; A1[1] = *(const float4*)(a1 + 4);
    const float* b0 = bp0 + (size_t)c * 32 * Kn;
    const float* b1 = bp1 + (size_t)c * 32 * Kn;
#pragma unroll
    for (int j = 0; j < 8; ++j) {
      B0[j] = b0[(size_t)j * Kn];            // 64B-coalesced across l15
      B1[j] = b1[(size_t)j * Kn];
    }
  };

  auto ssq4 = [](const float4& v) {
    return v.x*v.x + v.y*v.y + v.z*v.z + v.w*v.w;
  };

  auto consume = [&](float4 (&A0)[2], float4 (&A1)[2],
                     float (&B0)[8], float (&B1)[8]) {
    as0 += ssq4(A0[0]) + ssq4(A0[1]);
    as1 += ssq4(A1[0]) + ssq4(A1[1]);
#pragma unroll
    for (int j = 0; j < 8; ++j) { bs0 += B0[j]*B0[j]; bs1 += B1[j]*B1[j]; }

    union { unsigned d[4]; short8 v; } af0, af1, bf0, bf1;
    af0.d[0] = pack2(A0[0].x, A0[0].y); af0.d[1] = pack2(A0[0].z, A0[0].w);
    af0.d[2] = pack2(A0[1].x, A0[1].y); af0.d[3] = pack2(A0[1].z, A0[1].w);
    af1.d[0] = pack2(A1[0].x, A1[0].y); af1.d[1] = pack2(A1[0].z, A1[0].w);
    af1.d[2] = pack2(A1[1].x, A1[1].y); af1.d[3] = pack2(A1[1].z, A1[1].w);
    bf0.d[0] = pack2(B0[0], B0[1]); bf0.d[1] = pack2(B0[2], B0[3]);
    bf0.d[2] = pack2(B0[4], B0[5]); bf0.d[3] = pack2(B0[6], B0[7]);
    bf1.d[0] = pack2(B1[0], B1[1]); bf1.d[1] = pack2(B1[2], B1[3]);
    bf1.d[2] = pack2(B1[4], B1[5]); bf1.d[3] = pack2(B1[6], B1[7]);

    acc00 = __builtin_amdgcn_mfma_f32_16x16x32_bf16(af0.v, bf0.v, acc00, 0, 0, 0);
    acc01 = __builtin_amdgcn_mfma_f32_16x16x32_bf16(af0.v, bf1.v, acc01, 0, 0, 0);
    acc10 = __builtin_amdgcn_mfma_f32_16x16x32_bf16(af1.v, bf0.v, acc10, 0, 0, 0);
    acc11 = __builtin_amdgcn_mfma_f32_16x16x32_bf16(af1.v, bf1.v, acc11, 0, 0, 0);
  };

  // ---- barrier-free pipelined K-loop: 24 chunks of K=32, 2-deep regs ----
  load_chunk(0, cA0, cA1, cB0, cB1);
  for (int c = 0; c < 24; c += 2) {
    load_chunk(c + 1, pA0, pA1, pB0, pB1);
    consume(cA0, cA1, cB0, cB1);
    if (c + 2 < 24) load_chunk(c + 2, cA0, cA1, cB0, cB1);
    consume(pA0, pA1, pB0, pB1);
  }

  // ---- norm reduction: sum over the 4 quads (lanes l ^ 16, l ^ 32) ----
  as0 += __shfl_xor(as0, 16); as0 += __shfl_xor(as0, 32);
  as1 += __shfl_xor(as1, 16); as1 += __shfl_xor(as1, 32);
  bs0 += __shfl_xor(bs0, 16); bs0 += __shfl_xor(bs0, 32);
  bs1 += __shfl_xor(bs1, 16); bs1 += __shfl_xor(bs1, 32);
  // dedup: A slab shared by wn-pair -> wn==0 publishes; B by wm==0.
  if (wn == 0 && quad == 0) {
    AssqL[wm * 32 + l15]      = as0;
    AssqL[wm * 32 + l15 + 16] = as1;
  }
  if (wm == 0 && quad == 0) {
    BssqL[wn * 32 + l15]      = bs0;
    BssqL[wn * 32 + l15 + 16] = bs1;
  }
  __syncthreads();                           // only barrier in the kernel

  // ---- epilogue: scale by 1/max(||h_row||,eps) * 1/max(||w_col||,eps) ----
  // C/D layout: col = lane&15, row = quad*4 + reg
  const float wi0 = 1.0f / fmaxf(sqrtf(BssqL[wn * 32 + l15]),      1e-12f);
  const float wi1 = 1.0f / fmaxf(sqrtf(BssqL[wn * 32 + l15 + 16]), 1e-12f);

#pragma unroll
  for (int mi = 0; mi < 2; ++mi) {
#pragma unroll
    for (int r = 0; r < 4; ++r) {
      const int lr = wm * 32 + mi * 16 + quad * 4 + r;   // local row in tile
      const float hs = 1.0f / fmaxf(sqrtf(AssqL[lr]), 1e-12f);
      const float v0 = (mi ? acc10[r] : acc00[r]) * hs * wi0;
      const float v1 = (mi ? acc11[r] : acc01[r]) * hs * wi1;
      const int row = mt * 64 + lr;
      const size_t ob = ((size_t)row * Gn + g) * Kn + nt * 64;
      out[ob + wn * 32 + l15]      = v0;
      out[ob + wn * 32 + l15 + 16] = v1;
    }
  }
}

extern "C" void kernel_launch(void* const* d_in, const int* in_sizes, int n_in,
                              void* d_out, int out_size, void* d_ws, size_t ws_size,
                              hipStream_t stream) {
  const float* h = (const float*)d_in[0];          // [B,G,D]
  const float* W = (const float*)d_in[1];          // [G,D,K]
  float* out = (float*)d_out;                      // [B,G,K]
  hipLaunchKernelGGL(groupfc_kernel, dim3(4, 2, Gn), dim3(256), 0, stream, h, W, out);
}

// Round 5
// 170.135 us; speedup vs baseline: 1.1448x; 1.1448x over previous
//
#include <hip/hip_runtime.h>

// Problem constants: h[B,G,D], W[G,D,K], out[B,G,K]
#define Gn   100
#define Bn   256
#define Dn   768
#define Kn   128
#define BLDP 40   // B LDS leading dim in shorts (32+8)

typedef __attribute__((ext_vector_type(8))) short short8;
typedef __attribute__((ext_vector_type(4))) float f32x4;

// pack two fp32 -> two bf16 (round-to-nearest, ties away) in 3 VALU
__device__ inline unsigned pack2(float lo, float hi) {
  union { float f; unsigned u; } a, b; a.f = lo; b.f = hi;
  return __builtin_amdgcn_perm(b.u + 0x8000u, a.u + 0x8000u, 0x07060302u);
}

// async global->LDS DMA, 16 B per lane; dst is wave-uniform base + lane*16
__device__ inline void gload_lds16(const float* src, float* dst) {
  __builtin_amdgcn_global_load_lds(
      (const __attribute__((address_space(1))) void*)src,
      (__attribute__((address_space(3))) void*)dst, 16, 0, 0);
}

// Fused grouped GEMM, 64x64 tile, 4 waves (2x2), mfma_f32_16x16x32_bf16.
// A tiles: fp32 via global_load_lds (even-XOR granule swizzle; bf16 pack at
// fragment read). B tiles: register-staged bf16 (transposed [n][k] in LDS).
// Single barrier per K-step: DMA issued after the barrier is drained at the
// NEXT barrier, so loads have a full compute phase in flight.
// XCD swizzle: blockIdx%8 == g%8 -> all 8 tiles of a group share one XCD's L2.
__global__ __launch_bounds__(256) void groupfc_kernel(
    const float* __restrict__ h, const float* __restrict__ W,
    float* __restrict__ out) {
  // grid 832 = 104*8; decode: xcd=id%8 -> g%8, tile = (id>>3)%8
  const int id   = blockIdx.x;
  const int xcd  = id & 7;
  const int rest = id >> 3;
  const int tl   = rest & 7;
  const int g    = (rest >> 3) * 8 + xcd;
  if (g >= Gn) return;                       // 32 pad blocks exit whole
  const int mt   = tl >> 1;                  // 0..3 (rows of 64)
  const int nt   = tl & 1;                   // 0..1 (cols of 64)

  const int t    = threadIdx.x;
  const int lane = t & 63;
  const int wave = t >> 6;
  const int wm   = wave >> 1, wn = wave & 1; // 2x2 wave grid, 32x32 each
  const int l15  = lane & 15, quad = lane >> 4;

  __shared__ __align__(16) float Af[2][64 * 32];     // A fp32, swizzled granules
  __shared__ __align__(16) short Bf[2][64 * BLDP];   // B bf16, [n][k] padded
  __shared__ float AssqL[64];
  __shared__ float BssqL[4][64];

  // ---- A DMA lane mapping: instr j covers rows wave*16+j*8 .. +7 ----
  const int lr0 = wave * 16 + (lane >> 3);           // local row, instr 0
  const int lr1 = lr0 + 8;                           // local row, instr 1
  const int sg0 = (lane & 7) ^ ((lr0 & 3) << 1);     // swizzled granule
  const int sg1 = (lane & 7) ^ ((lr1 & 3) << 1);
  const float* asrc0 = h + ((size_t)(mt * 64 + lr0) * Gn + g) * Dn + sg0 * 4;
  const float* asrc1 = h + ((size_t)(mt * 64 + lr1) * Gn + g) * Dn + sg1 * 4;
  const int aoff0 = (wave * 16) * 32;                // uniform LDS float offset
  const int aoff1 = (wave * 16 + 8) * 32;

  // ---- B staging: thread (bk = n col, bq*8 = d base), coalesced across bk ----
  const int bk = t & 63;
  const int bq = t >> 6;                             // 0..3
  const float* bptr = W + (size_t)g * (Dn * Kn) + (size_t)(bq * 8) * Kn + nt * 64 + bk;

  f32x4 acc00 = {0.f,0.f,0.f,0.f};
  f32x4 acc01 = acc00, acc10 = acc00, acc11 = acc00;
  float as0 = 0.f, as1 = 0.f, bssq = 0.f;

  const int m0 = wm * 32 + l15;                      // A frag rows m0, m0+16
  const int n0 = wn * 32 + l15;                      // B frag cols n0, n0+16
  const int sA = (l15 & 3) << 1;                     // A frag granule swizzle
  const int ag = ((2 * quad) ^ sA) * 4;              // frag float offset in row

  float bv[8];

  // ---- prologue: chunk 0 ----
  gload_lds16(asrc0, &Af[0][aoff0]);
  gload_lds16(asrc1, &Af[0][aoff1]);
#pragma unroll
  for (int i = 0; i < 8; ++i) bv[i] = bptr[(size_t)i * Kn];
  {
    uint4 bp;
    bp.x = pack2(bv[0], bv[1]); bp.y = pack2(bv[2], bv[3]);
    bp.z = pack2(bv[4], bv[5]); bp.w = pack2(bv[6], bv[7]);
#pragma unroll
    for (int i = 0; i < 8; ++i) bssq += bv[i] * bv[i];
    *(uint4*)&Bf[0][bk * BLDP + bq * 8] = bp;
  }

  for (int c = 0; c < 24; ++c) {
    const int buf = c & 1;
    __syncthreads();   // chunk c DMA drained + B(c) writes visible + buf[1-cur] free

    if (c < 23) {      // issue chunk c+1: in flight for the whole compute phase
      const int d0 = (c + 1) * 32;
      gload_lds16(asrc0 + d0, &Af[1 - buf][aoff0]);
      gload_lds16(asrc1 + d0, &Af[1 - buf][aoff1]);
#pragma unroll
      for (int i = 0; i < 8; ++i) bv[i] = bptr[(size_t)(d0 + i) * Kn];
    }

    // ---- compute chunk c ----
    // A frags: fp32 from LDS (swizzled), ssq then pack to bf16
    f32x4 a0lo = *(const f32x4*)&Af[buf][m0 * 32 + ag];
    f32x4 a0hi = *(const f32x4*)&Af[buf][m0 * 32 + (ag ^ 16) + (((2*quad)&2)*0)];
    // NOTE: granule pair is contiguous: floats [ag, ag+8)
    a0hi = *(const f32x4*)&Af[buf][m0 * 32 + ag + 4];
    f32x4 a1lo = *(const f32x4*)&Af[buf][(m0 + 16) * 32 + ag];
    f32x4 a1hi = *(const f32x4*)&Af[buf][(m0 + 16) * 32 + ag + 4];

    as0 += a0lo.x*a0lo.x + a0lo.y*a0lo.y + a0lo.z*a0lo.z + a0lo.w*a0lo.w
         + a0hi.x*a0hi.x + a0hi.y*a0hi.y + a0hi.z*a0hi.z + a0hi.w*a0hi.w;
    as1 += a1lo.x*a1lo.x + a1lo.y*a1lo.y + a1lo.z*a1lo.z + a1lo.w*a1lo.w
         + a1hi.x*a1hi.x + a1hi.y*a1hi.y + a1hi.z*a1hi.z + a1hi.w*a1hi.w;

    union { unsigned d[4]; short8 v; } af0, af1;
    af0.d[0] = pack2(a0lo.x, a0lo.y); af0.d[1] = pack2(a0lo.z, a0lo.w);
    af0.d[2] = pack2(a0hi.x, a0hi.y); af0.d[3] = pack2(a0hi.z, a0hi.w);
    af1.d[0] = pack2(a1lo.x, a1lo.y); af1.d[1] = pack2(a1lo.z, a1lo.w);
    af1.d[2] = pack2(a1hi.x, a1hi.y); af1.d[3] = pack2(a1hi.z, a1hi.w);

    short8 bf0 = *(const short8*)&Bf[buf][n0 * BLDP + quad * 8];
    short8 bf1 = *(const short8*)&Bf[buf][(n0 + 16) * BLDP + quad * 8];

    acc00 = __builtin_amdgcn_mfma_f32_16x16x32_bf16(af0.v, bf0, acc00, 0, 0, 0);
    acc01 = __builtin_amdgcn_mfma_f32_16x16x32_bf16(af0.v, bf1, acc01, 0, 0, 0);
    acc10 = __builtin_amdgcn_mfma_f32_16x16x32_bf16(af1.v, bf0, acc10, 0, 0, 0);
    acc11 = __builtin_amdgcn_mfma_f32_16x16x32_bf16(af1.v, bf1, acc11, 0, 0, 0);

    // ---- pack & write B(c+1) (loads had the whole compute phase to land) ----
    if (c < 23) {
      uint4 bp;
      bp.x = pack2(bv[0], bv[1]); bp.y = pack2(bv[2], bv[3]);
      bp.z = pack2(bv[4], bv[5]); bp.w = pack2(bv[6], bv[7]);
#pragma unroll
      for (int i = 0; i < 8; ++i) bssq += bv[i] * bv[i];
      *(uint4*)&Bf[1 - buf][bk * BLDP + bq * 8] = bp;
    }
  }

  // ---- norm publication ----
  // A: quad-reduce (lanes ^16, ^32 sum the 4 quads); wn==0 publishes.
  as0 += __shfl_xor(as0, 16); as0 += __shfl_xor(as0, 32);
  as1 += __shfl_xor(as1, 16); as1 += __shfl_xor(as1, 32);
  if (wn == 0 && quad == 0) {
    AssqL[wm * 32 + l15]      = as0;
    AssqL[wm * 32 + l15 + 16] = as1;
  }
  // B: 4 threads (bq) share col bk.
  BssqL[bq][bk] = bssq;
  __syncthreads();

  // ---- epilogue: scale by 1/max(||h_row||,eps) * 1/max(||w_col||,eps) ----
  // C/D layout: col = lane&15, row = quad*4 + reg
  const float ws0 = BssqL[0][n0] + BssqL[1][n0] + BssqL[2][n0] + BssqL[3][n0];
  const float ws1 = BssqL[0][n0+16] + BssqL[1][n0+16] + BssqL[2][n0+16] + BssqL[3][n0+16];
  const float wi0 = 1.0f / fmaxf(sqrtf(ws0), 1e-12f);
  const float wi1 = 1.0f / fmaxf(sqrtf(ws1), 1e-12f);

#pragma unroll
  for (int mi = 0; mi < 2; ++mi) {
#pragma unroll
    for (int r = 0; r < 4; ++r) {
      const int lr = wm * 32 + mi * 16 + quad * 4 + r;    // local row in tile
      const float hs = 1.0f / fmaxf(sqrtf(AssqL[lr]), 1e-12f);
      const float v0 = (mi ? acc10[r] : acc00[r]) * hs * wi0;
      const float v1 = (mi ? acc11[r] : acc01[r]) * hs * wi1;
      const int row = mt * 64 + lr;
      const size_t ob = ((size_t)row * Gn + g) * Kn + nt * 64;
      out[ob + wn * 32 + l15]      = v0;
      out[ob + wn * 32 + l15 + 16] = v1;
    }
  }
}

extern "C" void kernel_launch(void* const* d_in, const int* in_sizes, int n_in,
                              void* d_out, int out_size, void* d_ws, size_t ws_size,
                              hipStream_t stream) {
  const float* h = (const float*)d_in[0];          // [B,G,D]
  const float* W = (const float*)d_in[1];          // [G,D,K]
  float* out = (float*)d_out;                      // [B,G,K]
  hipLaunchKernelGGL(groupfc_kernel, dim3(832), dim3(256), 0, stream, h, W, out);
}

// Round 6
// 169.512 us; speedup vs baseline: 1.1490x; 1.0037x over previous
//
#include <hip/hip_runtime.h>

// Problem constants: h[B,G,D], W[G,D,K], out[B,G,K]
#define Gn   100
#define Bn   256
#define Dn   768
#define Kn   128
#define LDP  40   // LDS leading dim in shorts (32+8): 2-way max bank aliasing (free)

typedef __attribute__((ext_vector_type(8))) short short8;
typedef __attribute__((ext_vector_type(4))) float f32x4;

// pack two fp32 -> two bf16 (round-to-nearest, ties away) in 3 VALU
__device__ inline unsigned pack2(float lo, float hi) {
  union { float f; unsigned u; } a, b; a.f = lo; b.f = hi;
  return __builtin_amdgcn_perm(b.u + 0x8000u, a.u + 0x8000u, 0x07060302u);
}

// Non-draining block barrier: execution sync + LDS-write visibility ONLY.
// __syncthreads() compiles to s_waitcnt vmcnt(0) lgkmcnt(0); s_barrier, which
// drains every in-flight global load each K-step (the measured 61 µs plateau
// across R2/R3/R5). All global loads here target registers (per-wave private),
// so skipping the vmcnt drain is safe; lgkmcnt(0) makes LDS stores visible.
__device__ inline void barrier_nodrain() {
  asm volatile("s_waitcnt lgkmcnt(0)\n\ts_barrier" ::: "memory");
}

// Fused grouped GEMM, 64x64 tile, 4 waves (2x2), mfma_f32_16x16x32_bf16.
// Register staging for A and B (fp32 ssq + bf16 pack in regs), triple-buffered
// LDS, ONE non-draining barrier per K-step. Loads for chunk c+2 issued at
// iter c stay in flight across two barriers (~2 iterations of latency cover);
// compiler inserts only minimal vmcnt(N) register-dep waits at the pack step.
// XCD swizzle: blockIdx%8 == g%8 -> group tiles share one XCD's L2 (R5: 57 MB FETCH).
__global__ __launch_bounds__(256) void groupfc_kernel(
    const float* __restrict__ h, const float* __restrict__ W,
    float* __restrict__ out) {
  // grid 832 = 104*8; decode: xcd=id%8 -> g%8, tile = (id>>3)%8
  const int id   = blockIdx.x;
  const int xcd  = id & 7;
  const int rest = id >> 3;
  const int tl   = rest & 7;
  const int g    = (rest >> 3) * 8 + xcd;
  if (g >= Gn) return;                       // pad blocks exit before any barrier
  const int mt   = tl >> 1;                  // 0..3 (rows of 64)
  const int nt   = tl & 1;                   // 0..1 (cols of 64)

  const int t    = threadIdx.x;
  const int lane = t & 63;
  const int wave = t >> 6;
  const int wm   = wave >> 1, wn = wave & 1; // 2x2 wave grid, 32x32 each
  const int l15  = lane & 15, quad = lane >> 4;

  __shared__ __align__(16) short Af[3][64 * LDP];  // [m][k] bf16, 3 buffers
  __shared__ __align__(16) short Bf[3][64 * LDP];  // [n][k] bf16, 3 buffers
  __shared__ float AssqL[64];
  __shared__ float BssqL[4][64];

  f32x4 acc00 = {0.f,0.f,0.f,0.f};
  f32x4 acc01 = acc00, acc10 = acc00, acc11 = acc00;

  // A staging: thread -> (row ar, 8 contiguous k at ac); two dwordx4 per chunk
  const int ar = t >> 2;
  const int ac = (t & 3) * 8;
  const float* aptr = h + ((size_t)(mt * 64 + ar) * Gn + g) * Dn + ac;
  // B staging: thread -> (col bk, 8 k at bq*8); coalesced across bk lanes
  const int bk = t & 63;
  const int bq = t >> 6;
  const float* bptr = W + (size_t)g * (Dn * Kn) + (size_t)(bq * 8) * Kn + nt * 64 + bk;

  const int koff = quad * 8;                 // A/B fragment: k = quad*8 + j
  const int m0   = wm * 32 + l15;
  const int n0   = wn * 32 + l15;

  float assq = 0.f, bssq = 0.f;
  float4 Ar[2][2];                           // 2 register sets (chunks c+1, c+2)
  float  Br[2][8];

  auto load_set = [&](int c, int s) {        // issue chunk-c loads into set s
    const int d0 = c * 32;
    Ar[s][0] = *(const float4*)(aptr + d0);
    Ar[s][1] = *(const float4*)(aptr + d0 + 4);
#pragma unroll
    for (int i = 0; i < 8; ++i) Br[s][i] = bptr[(size_t)(d0 + i) * Kn];
  };

  auto pack_set = [&](int c, int s) {        // fp32 ssq + bf16 pack -> buf[c%3]
    const float4 a0 = Ar[s][0], a1 = Ar[s][1];
    assq += a0.x*a0.x + a0.y*a0.y + a0.z*a0.z + a0.w*a0.w
          + a1.x*a1.x + a1.y*a1.y + a1.z*a1.z + a1.w*a1.w;
    uint4 ap;
    ap.x = pack2(a0.x, a0.y); ap.y = pack2(a0.z, a0.w);
    ap.z = pack2(a1.x, a1.y); ap.w = pack2(a1.z, a1.w);
    *(uint4*)&Af[c % 3][ar * LDP + ac] = ap;

    uint4 bp;
    bp.x = pack2(Br[s][0], Br[s][1]); bp.y = pack2(Br[s][2], Br[s][3]);
    bp.z = pack2(Br[s][4], Br[s][5]); bp.w = pack2(Br[s][6], Br[s][7]);
#pragma unroll
    for (int i = 0; i < 8; ++i) bssq += Br[s][i] * Br[s][i];
    *(uint4*)&Bf[c % 3][bk * LDP + bq * 8] = bp;
  };

  // ---- prologue: chunks 0,1 in flight; pack 0 ----
  load_set(0, 0);
  load_set(1, 1);
  pack_set(0, 0);

  // ---- main loop: 24 K-steps, ONE non-draining barrier each ----
  // Window [bar(c), bar(c+1)] reads buf[c%3], writes buf[(c+2)%3]: disjoint.
#pragma unroll
  for (int c = 0; c < 24; ++c) {
    if (c + 2 < 24) load_set(c + 2, c & 1);      // 2-barrier-deep prefetch
    if (c + 1 < 24) pack_set(c + 1, (c + 1) & 1);
    barrier_nodrain();

    const int b = c % 3;
    short8 af0 = *(const short8*)&Af[b][m0 * LDP + koff];
    short8 af1 = *(const short8*)&Af[b][(m0 + 16) * LDP + koff];
    short8 bf0 = *(const short8*)&Bf[b][n0 * LDP + koff];
    short8 bf1 = *(const short8*)&Bf[b][(n0 + 16) * LDP + koff];

    acc00 = __builtin_amdgcn_mfma_f32_16x16x32_bf16(af0, bf0, acc00, 0, 0, 0);
    acc01 = __builtin_amdgcn_mfma_f32_16x16x32_bf16(af0, bf1, acc01, 0, 0, 0);
    acc10 = __builtin_amdgcn_mfma_f32_16x16x32_bf16(af1, bf0, acc10, 0, 0, 0);
    acc11 = __builtin_amdgcn_mfma_f32_16x16x32_bf16(af1, bf1, acc11, 0, 0, 0);
  }

  // ---- block-reduce the norms ----
  assq += __shfl_xor(assq, 1);               // 4 threads (t&3) share row ar
  assq += __shfl_xor(assq, 2);
  if ((t & 3) == 0) AssqL[ar] = assq;
  BssqL[bq][bk] = bssq;                      // 4 waves (bq) share col bk
  __syncthreads();                           // one draining barrier: loop is done

  // ---- epilogue: scale by 1/max(||h_row||,eps) * 1/max(||w_col||,eps) ----
  // C/D layout: col = lane&15, row = quad*4 + reg
  const float ws0 = BssqL[0][n0] + BssqL[1][n0] + BssqL[2][n0] + BssqL[3][n0];
  const float ws1 = BssqL[0][n0+16] + BssqL[1][n0+16] + BssqL[2][n0+16] + BssqL[3][n0+16];
  const float wi0 = 1.0f / fmaxf(sqrtf(ws0), 1e-12f);
  const float wi1 = 1.0f / fmaxf(sqrtf(ws1), 1e-12f);

#pragma unroll
  for (int mi = 0; mi < 2; ++mi) {
#pragma unroll
    for (int r = 0; r < 4; ++r) {
      const int lr = wm * 32 + mi * 16 + quad * 4 + r;   // local row in tile
      const float hs = 1.0f / fmaxf(sqrtf(AssqL[lr]), 1e-12f);
      const float v0 = (mi ? acc10[r] : acc00[r]) * hs * wi0;
      const float v1 = (mi ? acc11[r] : acc01[r]) * hs * wi1;
      const int row = mt * 64 + lr;
      const size_t ob = ((size_t)row * Gn + g) * Kn + nt * 64;
      out[ob + wn * 32 + l15]      = v0;
      out[ob + wn * 32 + l15 + 16] = v1;
    }
  }
}

extern "C" void kernel_launch(void* const* d_in, const int* in_sizes, int n_in,
                              void* d_out, int out_size, void* d_ws, size_t ws_size,
                              hipStream_t stream) {
  const float* h = (const float*)d_in[0];          // [B,G,D]
  const float* W = (const float*)d_in[1];          // [G,D,K]
  float* out = (float*)d_out;                      // [B,G,K]
  hipLaunchKernelGGL(groupfc_kernel, dim3(832), dim3(256), 0, stream, h, W, out);
}